// Round 3
// baseline (7407.100 us; speedup 1.0000x reference)
//
#include <hip/hip_runtime.h>
#include <hip/hip_bf16.h>

// N_NODES=50000, N_EDGES=1600000, ATOM_F=64, FP_SIZE=2048, N_GRAPHS=2000
#define AF 64
#define NFP 2048

// ---------------------------------------------------------------------------
// Generic histogram (int32 keys)
// ---------------------------------------------------------------------------
__global__ __launch_bounds__(256) void hist_kernel(
    const int* __restrict__ keys, int* __restrict__ counts, int n)
{
    int e = blockIdx.x * 256 + threadIdx.x;
    if (e < n) atomicAdd(&counts[keys[e]], 1);
}

// single-block exclusive scan, in place; data[n] = total
__global__ __launch_bounds__(1024) void scan_kernel(int* data, int n)
{
    __shared__ int wsum[16];
    __shared__ int chunk_total;
    int t = threadIdx.x, lane = t & 63, w = t >> 6;
    int running = 0;
    for (int base = 0; base < n; base += 1024) {
        int i = base + t;
        int v = (i < n) ? data[i] : 0;
        int x = v;
        #pragma unroll
        for (int off = 1; off < 64; off <<= 1) {
            int y = __shfl_up(x, off);
            if (lane >= off) x += y;
        }
        if (lane == 63) wsum[w] = x;
        __syncthreads();
        if (t == 0) {
            int s = 0;
            #pragma unroll
            for (int q = 0; q < 16; ++q) { int tmp = wsum[q]; wsum[q] = s; s += tmp; }
            chunk_total = s;
        }
        __syncthreads();
        if (i < n) data[i] = x - v + wsum[w] + running;
        running += chunk_total;
        __syncthreads();
    }
    if (t == 0) data[n] = running;
}

__global__ __launch_bounds__(256) void scatter_ids_kernel(
    const int* __restrict__ src, const int* __restrict__ dst,
    int* __restrict__ cursor, int* __restrict__ esrc, int n_edges)
{
    int e = blockIdx.x * 256 + threadIdx.x;
    if (e < n_edges) {
        int pos = atomicAdd(&cursor[dst[e]], 1);
        esrc[pos] = src[e];
    }
}

// ---------------------------------------------------------------------------
// Transpose Ww [2048][64] -> WwT [64][2048]
// ---------------------------------------------------------------------------
__global__ __launch_bounds__(256) void transpose64_kernel(
    const float* __restrict__ W, float* __restrict__ WT)
{
    __shared__ float tile[64][65];
    int j0 = blockIdx.x * 64;
    int t = threadIdx.x;
    for (int idx = t; idx < 4096; idx += 256) {
        int r = idx >> 6, k = idx & 63;
        tile[r][k] = W[(size_t)(j0 + r) * AF + k];
    }
    __syncthreads();
    for (int idx = t; idx < 4096; idx += 256) {
        int k = idx >> 6, r = idx & 63;
        WT[(size_t)k * NFP + j0 + r] = tile[r][k];
    }
}

// ---------------------------------------------------------------------------
// Fused gather-aggregate (CSR, no atomics) + self-loop + 64x64 sigmoid MLP.
// ---------------------------------------------------------------------------
__global__ __launch_bounds__(256) void agg_mlp_kernel(
    const float* __restrict__ h, const int* __restrict__ offsets,
    const int* __restrict__ esrc, const float* __restrict__ Hw,
    const float* __restrict__ Hb, float* __restrict__ out, int n_nodes)
{
    __shared__ float Hw_s[AF * 65];
    __shared__ __align__(16) float part[4][4][AF];
    __shared__ float a_red[4][AF];
    __shared__ float hb_s[AF];

    int t = threadIdx.x;
    for (int idx = t; idx < AF * AF; idx += 256) {
        int j = idx >> 6, k = idx & 63;
        Hw_s[j * 65 + k] = Hw[idx];
    }
    if (t < AF) hb_s[t] = Hb[t];

    int w = t >> 6, lane = t & 63;
    int sub = lane >> 4, f4 = lane & 15;
    int i = blockIdx.x * 4 + w;

    float4 acc = make_float4(0.f, 0.f, 0.f, 0.f);
    if (i < n_nodes) {
        int o0 = offsets[i], o1 = offsets[i + 1];
        const int* ep = esrc + o0;
        int deg = o1 - o0;
        const float4* h4 = (const float4*)h;
        int j = 0;
        for (; j + 4 <= deg; j += 4) {
            int s = ep[j + sub];
            float4 v = h4[(size_t)s * 16 + f4];
            acc.x += v.x; acc.y += v.y; acc.z += v.z; acc.w += v.w;
        }
        if (j + sub < deg) {
            int s = ep[j + sub];
            float4 v = h4[(size_t)s * 16 + f4];
            acc.x += v.x; acc.y += v.y; acc.z += v.z; acc.w += v.w;
        }
    }
    *(float4*)&part[w][sub][f4 * 4] = acc;
    __syncthreads();

    if (i < n_nodes) {
        float val = h[(size_t)i * AF + lane]
                  + part[w][0][lane] + part[w][1][lane]
                  + part[w][2][lane] + part[w][3][lane];
        a_red[w][lane] = val;
    }
    __syncthreads();

    if (i < n_nodes) {
        float z = hb_s[lane];
        #pragma unroll
        for (int k = 0; k < AF; ++k)
            z = fmaf(a_red[w][k], Hw_s[lane * 65 + k], z);
        out[(size_t)i * AF + lane] = 1.f / (1.f + __expf(-z));
    }
}

// ---------------------------------------------------------------------------
// Fingerprint + softmax + pooling: ONE BLOCK PER GRAPH (batch is sorted, so
// each graph is a contiguous node range [goff[g], goff[g+1])). Block loops
// over its nodes in chunks of 8 with the register-tiled GEMM, pools into LDS
// facc, and writes its out-row exactly once — ZERO output atomics.
// ACCUM=0: out = facc (layer 1).  ACCUM=1: out += facc (layer 2).
// ---------------------------------------------------------------------------
template <int ACCUM>
__global__ __launch_bounds__(256) void fp_pool_graph_kernel(
    const float* __restrict__ upd, const float* __restrict__ WwT,
    const float* __restrict__ Wb, const int* __restrict__ goff,
    float* __restrict__ out)
{
    __shared__ __align__(16) float upd_s[8][AF];
    __shared__ __align__(16) float facc[NFP];
    __shared__ float wred[4];

    int t = threadIdx.x, wave = t >> 6, lane = t & 63;
    int g = blockIdx.x;
    int gs = goff[g], ge = goff[g + 1];

    #pragma unroll
    for (int r = 0; r < 8; ++r) facc[r * 256 + t] = 0.f;

    float4 ba = *(const float4*)&Wb[t * 4];
    float4 bb = *(const float4*)&Wb[1024 + t * 4];

    for (int i0 = gs; i0 < ge; i0 += 8) {
        int nvalid = ge - i0;
        if (nvalid > 8) nvalid = 8;

        __syncthreads();  // protect upd_s from previous chunk's readers
        for (int idx = t; idx < 128; idx += 256) {
            int n = idx >> 4, q = idx & 15;
            float4 v = make_float4(0.f, 0.f, 0.f, 0.f);
            if (n < nvalid) v = *(const float4*)&upd[(size_t)(i0 + n) * AF + q * 4];
            *(float4*)&upd_s[n][q * 4] = v;
        }
        __syncthreads();

        float4 accA[8], accB[8];
        #pragma unroll
        for (int n = 0; n < 8; ++n) { accA[n] = ba; accB[n] = bb; }

        #pragma unroll 2
        for (int k4 = 0; k4 < 16; ++k4) {
            float4 u4[8];
            #pragma unroll
            for (int n = 0; n < 8; ++n) u4[n] = *(const float4*)&upd_s[n][k4 * 4];
            #pragma unroll
            for (int c = 0; c < 4; ++c) {
                int k = k4 * 4 + c;
                float4 wa = *(const float4*)&WwT[(size_t)k * NFP + t * 4];
                float4 wb = *(const float4*)&WwT[(size_t)k * NFP + 1024 + t * 4];
                #pragma unroll
                for (int n = 0; n < 8; ++n) {
                    float u = (c == 0) ? u4[n].x : (c == 1) ? u4[n].y
                            : (c == 2) ? u4[n].z : u4[n].w;
                    accA[n].x = fmaf(u, wa.x, accA[n].x);
                    accA[n].y = fmaf(u, wa.y, accA[n].y);
                    accA[n].z = fmaf(u, wa.z, accA[n].z);
                    accA[n].w = fmaf(u, wa.w, accA[n].w);
                    accB[n].x = fmaf(u, wb.x, accB[n].x);
                    accB[n].y = fmaf(u, wb.y, accB[n].y);
                    accB[n].z = fmaf(u, wb.z, accB[n].z);
                    accB[n].w = fmaf(u, wb.w, accB[n].w);
                }
            }
        }

        for (int n = 0; n < nvalid; ++n) {
            float m = fmaxf(fmaxf(fmaxf(accA[n].x, accA[n].y), fmaxf(accA[n].z, accA[n].w)),
                            fmaxf(fmaxf(accB[n].x, accB[n].y), fmaxf(accB[n].z, accB[n].w)));
            #pragma unroll
            for (int off = 32; off >= 1; off >>= 1) m = fmaxf(m, __shfl_xor(m, off));
            if (lane == 0) wred[wave] = m;
            __syncthreads();
            m = fmaxf(fmaxf(wred[0], wred[1]), fmaxf(wred[2], wred[3]));
            __syncthreads();

            float4 ea, eb;
            ea.x = __expf(accA[n].x - m); ea.y = __expf(accA[n].y - m);
            ea.z = __expf(accA[n].z - m); ea.w = __expf(accA[n].w - m);
            eb.x = __expf(accB[n].x - m); eb.y = __expf(accB[n].y - m);
            eb.z = __expf(accB[n].z - m); eb.w = __expf(accB[n].w - m);
            float s = ea.x + ea.y + ea.z + ea.w + eb.x + eb.y + eb.z + eb.w;
            #pragma unroll
            for (int off = 32; off >= 1; off >>= 1) s += __shfl_xor(s, off);
            if (lane == 0) wred[wave] = s;
            __syncthreads();
            s = wred[0] + wred[1] + wred[2] + wred[3];
            float inv = 1.f / s;

            float4 fa = *(float4*)&facc[t * 4];          // thread-exclusive slots
            fa.x += ea.x * inv; fa.y += ea.y * inv;
            fa.z += ea.z * inv; fa.w += ea.w * inv;
            *(float4*)&facc[t * 4] = fa;
            float4 fb = *(float4*)&facc[1024 + t * 4];
            fb.x += eb.x * inv; fb.y += eb.y * inv;
            fb.z += eb.z * inv; fb.w += eb.w * inv;
            *(float4*)&facc[1024 + t * 4] = fb;
            __syncthreads();  // protect wred before next node
        }
    }

    float* po = &out[(size_t)g * NFP];
    float4 fa = *(float4*)&facc[t * 4];
    float4 fb = *(float4*)&facc[1024 + t * 4];
    if (ACCUM) {
        float4 oa = *(float4*)&po[t * 4];
        float4 ob = *(float4*)&po[1024 + t * 4];
        fa.x += oa.x; fa.y += oa.y; fa.z += oa.z; fa.w += oa.w;
        fb.x += ob.x; fb.y += ob.y; fb.z += ob.z; fb.w += ob.w;
    }
    *(float4*)&po[t * 4] = fa;
    *(float4*)&po[1024 + t * 4] = fb;
}

// ---------------------------------------------------------------------------
extern "C" void kernel_launch(void* const* d_in, const int* in_sizes, int n_in,
                              void* d_out, int out_size, void* d_ws, size_t ws_size,
                              hipStream_t stream)
{
    const float* x    = (const float*)d_in[0];
    const float* H1_w = (const float*)d_in[1];
    const float* H1_b = (const float*)d_in[2];
    const float* W1_w = (const float*)d_in[3];
    const float* W1_b = (const float*)d_in[4];
    const float* H2_w = (const float*)d_in[5];
    const float* H2_b = (const float*)d_in[6];
    const float* W2_w = (const float*)d_in[7];
    const float* W2_b = (const float*)d_in[8];
    const int*   ei   = (const int*)d_in[9];
    const int*   batch= (const int*)d_in[10];

    const int n_nodes  = in_sizes[0] / AF;   // 50000
    const int n_edges  = in_sizes[9] / 2;    // 1600000
    const int n_graphs = out_size / NFP;     // 2000
    const int* src = ei;
    const int* dst = ei + n_edges;
    float* out = (float*)d_out;

    // workspace layout
    float* bufA    = (float*)d_ws;                          // 3.2M floats
    float* bufB    = bufA + (size_t)n_nodes * AF;           // 3.2M floats
    float* WwT1    = bufB + (size_t)n_nodes * AF;           // 131072
    float* WwT2    = WwT1 + (size_t)AF * NFP;               // 131072
    int*   offsets = (int*)(WwT2 + (size_t)AF * NFP);       // n_nodes+1
    int*   cursor  = offsets + (n_nodes + 1);               // n_nodes+1
    int*   goff    = cursor + (n_nodes + 1);                // n_graphs+1
    int*   esrc    = goff + (n_graphs + 1);                 // n_edges

    const int eb = (n_edges + 255) / 256;
    const int nb = (n_nodes + 255) / 256;
    const int mlp_blocks = (n_nodes + 3) / 4;

    // --- one-time per launch: transposes + CSR + graph offsets ---
    transpose64_kernel<<<NFP / 64, 256, 0, stream>>>(W1_w, WwT1);
    transpose64_kernel<<<NFP / 64, 256, 0, stream>>>(W2_w, WwT2);
    hipMemsetAsync(offsets, 0, (size_t)(n_nodes + 1) * sizeof(int), stream);
    hipMemsetAsync(goff, 0, (size_t)(n_graphs + 1) * sizeof(int), stream);
    hist_kernel<<<eb, 256, 0, stream>>>(dst, offsets, n_edges);
    hist_kernel<<<nb, 256, 0, stream>>>(batch, goff, n_nodes);
    scan_kernel<<<1, 1024, 0, stream>>>(offsets, n_nodes);
    scan_kernel<<<1, 1024, 0, stream>>>(goff, n_graphs);
    hipMemcpyAsync(cursor, offsets, (size_t)n_nodes * sizeof(int),
                   hipMemcpyDeviceToDevice, stream);
    scatter_ids_kernel<<<eb, 256, 0, stream>>>(src, dst, cursor, esrc, n_edges);

    // --- layer 1 ---
    agg_mlp_kernel<<<mlp_blocks, 256, 0, stream>>>(x, offsets, esrc, H1_w, H1_b, bufB, n_nodes);
    fp_pool_graph_kernel<0><<<n_graphs, 256, 0, stream>>>(bufB, WwT1, W1_b, goff, out);

    // --- layer 2 ---
    agg_mlp_kernel<<<mlp_blocks, 256, 0, stream>>>(bufB, offsets, esrc, H2_w, H2_b, bufA, n_nodes);
    fp_pool_graph_kernel<1><<<n_graphs, 256, 0, stream>>>(bufA, WwT2, W2_b, goff, out);
}

// Round 4
// 1123.713 us; speedup vs baseline: 6.5916x; 6.5916x over previous
//
#include <hip/hip_runtime.h>
#include <hip/hip_bf16.h>

// N_NODES=50000, N_EDGES=1600000, ATOM_F=64, FP_SIZE=2048, N_GRAPHS=2000
#define AF 64
#define NFP 2048

// ---------------------------------------------------------------------------
// Generic histogram (int32 keys)
// ---------------------------------------------------------------------------
__global__ __launch_bounds__(256) void hist_kernel(
    const int* __restrict__ keys, int* __restrict__ counts, int n)
{
    int e = blockIdx.x * 256 + threadIdx.x;
    if (e < n) atomicAdd(&counts[keys[e]], 1);
}

// single-block exclusive scan, in place; data[n] = total
__global__ __launch_bounds__(1024) void scan_kernel(int* data, int n)
{
    __shared__ int wsum[16];
    __shared__ int chunk_total;
    int t = threadIdx.x, lane = t & 63, w = t >> 6;
    int running = 0;
    for (int base = 0; base < n; base += 1024) {
        int i = base + t;
        int v = (i < n) ? data[i] : 0;
        int x = v;
        #pragma unroll
        for (int off = 1; off < 64; off <<= 1) {
            int y = __shfl_up(x, off);
            if (lane >= off) x += y;
        }
        if (lane == 63) wsum[w] = x;
        __syncthreads();
        if (t == 0) {
            int s = 0;
            #pragma unroll
            for (int q = 0; q < 16; ++q) { int tmp = wsum[q]; wsum[q] = s; s += tmp; }
            chunk_total = s;
        }
        __syncthreads();
        if (i < n) data[i] = x - v + wsum[w] + running;
        running += chunk_total;
        __syncthreads();
    }
    if (t == 0) data[n] = running;
}

__global__ __launch_bounds__(256) void scatter_ids_kernel(
    const int* __restrict__ src, const int* __restrict__ dst,
    int* __restrict__ cursor, int* __restrict__ esrc, int n_edges)
{
    int e = blockIdx.x * 256 + threadIdx.x;
    if (e < n_edges) {
        int pos = atomicAdd(&cursor[dst[e]], 1);
        esrc[pos] = src[e];
    }
}

// ---------------------------------------------------------------------------
// Transpose Ww [2048][64] -> WwT [64][2048]
// ---------------------------------------------------------------------------
__global__ __launch_bounds__(256) void transpose64_kernel(
    const float* __restrict__ W, float* __restrict__ WT)
{
    __shared__ float tile[64][65];
    int j0 = blockIdx.x * 64;
    int t = threadIdx.x;
    for (int idx = t; idx < 4096; idx += 256) {
        int r = idx >> 6, k = idx & 63;
        tile[r][k] = W[(size_t)(j0 + r) * AF + k];
    }
    __syncthreads();
    for (int idx = t; idx < 4096; idx += 256) {
        int k = idx >> 6, r = idx & 63;
        WT[(size_t)k * NFP + j0 + r] = tile[r][k];
    }
}

// ---------------------------------------------------------------------------
// Fused gather-aggregate (CSR, no atomics) + self-loop + 64x64 sigmoid MLP.
// ---------------------------------------------------------------------------
__global__ __launch_bounds__(256) void agg_mlp_kernel(
    const float* __restrict__ h, const int* __restrict__ offsets,
    const int* __restrict__ esrc, const float* __restrict__ Hw,
    const float* __restrict__ Hb, float* __restrict__ out, int n_nodes)
{
    __shared__ float Hw_s[AF * 65];
    __shared__ __align__(16) float part[4][4][AF];
    __shared__ float a_red[4][AF];
    __shared__ float hb_s[AF];

    int t = threadIdx.x;
    for (int idx = t; idx < AF * AF; idx += 256) {
        int j = idx >> 6, k = idx & 63;
        Hw_s[j * 65 + k] = Hw[idx];
    }
    if (t < AF) hb_s[t] = Hb[t];

    int w = t >> 6, lane = t & 63;
    int sub = lane >> 4, f4 = lane & 15;
    int i = blockIdx.x * 4 + w;

    float4 acc = make_float4(0.f, 0.f, 0.f, 0.f);
    if (i < n_nodes) {
        int o0 = offsets[i], o1 = offsets[i + 1];
        const int* ep = esrc + o0;
        int deg = o1 - o0;
        const float4* h4 = (const float4*)h;
        int j = 0;
        for (; j + 4 <= deg; j += 4) {
            int s = ep[j + sub];
            float4 v = h4[(size_t)s * 16 + f4];
            acc.x += v.x; acc.y += v.y; acc.z += v.z; acc.w += v.w;
        }
        if (j + sub < deg) {
            int s = ep[j + sub];
            float4 v = h4[(size_t)s * 16 + f4];
            acc.x += v.x; acc.y += v.y; acc.z += v.z; acc.w += v.w;
        }
    }
    *(float4*)&part[w][sub][f4 * 4] = acc;
    __syncthreads();

    if (i < n_nodes) {
        float val = h[(size_t)i * AF + lane]
                  + part[w][0][lane] + part[w][1][lane]
                  + part[w][2][lane] + part[w][3][lane];
        a_red[w][lane] = val;
    }
    __syncthreads();

    if (i < n_nodes) {
        float z = hb_s[lane];
        #pragma unroll
        for (int k = 0; k < AF; ++k)
            z = fmaf(a_red[w][k], Hw_s[lane * 65 + k], z);
        out[(size_t)i * AF + lane] = 1.f / (1.f + __expf(-z));
    }
}

// ---------------------------------------------------------------------------
// Fingerprint + softmax + pooling: one block per graph, zero output atomics.
// All acc indexing is COMPILE-TIME (softmax loop fully unrolled, each copy
// guarded by block-uniform n < nvalid) so acc stays in VGPRs — rule #20.
// ---------------------------------------------------------------------------
template <int ACCUM>
__global__ __launch_bounds__(256) void fp_pool_graph_kernel(
    const float* __restrict__ upd, const float* __restrict__ WwT,
    const float* __restrict__ Wb, const int* __restrict__ goff,
    float* __restrict__ out)
{
    __shared__ __align__(16) float upd_s[8][AF];
    __shared__ __align__(16) float facc[NFP];
    __shared__ float wred[4];

    int t = threadIdx.x, wave = t >> 6, lane = t & 63;
    int g = blockIdx.x;
    int gs = goff[g], ge = goff[g + 1];

    #pragma unroll
    for (int r = 0; r < 8; ++r) facc[r * 256 + t] = 0.f;

    float4 ba = *(const float4*)&Wb[t * 4];
    float4 bb = *(const float4*)&Wb[1024 + t * 4];

    for (int i0 = gs; i0 < ge; i0 += 8) {
        int nvalid = ge - i0;             // block-uniform
        if (nvalid > 8) nvalid = 8;

        __syncthreads();  // protect upd_s from previous chunk's readers
        for (int idx = t; idx < 128; idx += 256) {
            int n = idx >> 4, q = idx & 15;
            float4 v = make_float4(0.f, 0.f, 0.f, 0.f);
            if (n < nvalid) v = *(const float4*)&upd[(size_t)(i0 + n) * AF + q * 4];
            *(float4*)&upd_s[n][q * 4] = v;
        }
        __syncthreads();

        float4 accA[8], accB[8];
        #pragma unroll
        for (int n = 0; n < 8; ++n) { accA[n] = ba; accB[n] = bb; }

        #pragma unroll 2
        for (int k4 = 0; k4 < 16; ++k4) {
            float4 u4[8];
            #pragma unroll
            for (int n = 0; n < 8; ++n) u4[n] = *(const float4*)&upd_s[n][k4 * 4];
            #pragma unroll
            for (int c = 0; c < 4; ++c) {
                int k = k4 * 4 + c;
                float4 wa = *(const float4*)&WwT[(size_t)k * NFP + t * 4];
                float4 wb = *(const float4*)&WwT[(size_t)k * NFP + 1024 + t * 4];
                #pragma unroll
                for (int n = 0; n < 8; ++n) {
                    float u = (c == 0) ? u4[n].x : (c == 1) ? u4[n].y
                            : (c == 2) ? u4[n].z : u4[n].w;
                    accA[n].x = fmaf(u, wa.x, accA[n].x);
                    accA[n].y = fmaf(u, wa.y, accA[n].y);
                    accA[n].z = fmaf(u, wa.z, accA[n].z);
                    accA[n].w = fmaf(u, wa.w, accA[n].w);
                    accB[n].x = fmaf(u, wb.x, accB[n].x);
                    accB[n].y = fmaf(u, wb.y, accB[n].y);
                    accB[n].z = fmaf(u, wb.z, accB[n].z);
                    accB[n].w = fmaf(u, wb.w, accB[n].w);
                }
            }
        }

        // softmax + pool: FULLY UNROLLED, static acc indices (keeps acc in VGPRs)
        #pragma unroll
        for (int n = 0; n < 8; ++n) {
            if (n < nvalid) {   // block-uniform guard
                float m = fmaxf(fmaxf(fmaxf(accA[n].x, accA[n].y), fmaxf(accA[n].z, accA[n].w)),
                                fmaxf(fmaxf(accB[n].x, accB[n].y), fmaxf(accB[n].z, accB[n].w)));
                #pragma unroll
                for (int off = 32; off >= 1; off >>= 1) m = fmaxf(m, __shfl_xor(m, off));
                if (lane == 0) wred[wave] = m;
                __syncthreads();
                m = fmaxf(fmaxf(wred[0], wred[1]), fmaxf(wred[2], wred[3]));
                __syncthreads();

                float4 ea, eb;
                ea.x = __expf(accA[n].x - m); ea.y = __expf(accA[n].y - m);
                ea.z = __expf(accA[n].z - m); ea.w = __expf(accA[n].w - m);
                eb.x = __expf(accB[n].x - m); eb.y = __expf(accB[n].y - m);
                eb.z = __expf(accB[n].z - m); eb.w = __expf(accB[n].w - m);
                float s = ea.x + ea.y + ea.z + ea.w + eb.x + eb.y + eb.z + eb.w;
                #pragma unroll
                for (int off = 32; off >= 1; off >>= 1) s += __shfl_xor(s, off);
                if (lane == 0) wred[wave] = s;
                __syncthreads();
                s = wred[0] + wred[1] + wred[2] + wred[3];
                float inv = 1.f / s;

                float4 fa = *(float4*)&facc[t * 4];      // thread-exclusive slots
                fa.x += ea.x * inv; fa.y += ea.y * inv;
                fa.z += ea.z * inv; fa.w += ea.w * inv;
                *(float4*)&facc[t * 4] = fa;
                float4 fb = *(float4*)&facc[1024 + t * 4];
                fb.x += eb.x * inv; fb.y += eb.y * inv;
                fb.z += eb.z * inv; fb.w += eb.w * inv;
                *(float4*)&facc[1024 + t * 4] = fb;
                __syncthreads();  // protect wred before next node
            }
        }
    }

    float* po = &out[(size_t)g * NFP];
    float4 fa = *(float4*)&facc[t * 4];
    float4 fb = *(float4*)&facc[1024 + t * 4];
    if (ACCUM) {
        float4 oa = *(float4*)&po[t * 4];
        float4 ob = *(float4*)&po[1024 + t * 4];
        fa.x += oa.x; fa.y += oa.y; fa.z += oa.z; fa.w += oa.w;
        fb.x += ob.x; fb.y += ob.y; fb.z += ob.z; fb.w += ob.w;
    }
    *(float4*)&po[t * 4] = fa;
    *(float4*)&po[1024 + t * 4] = fb;
}

// ---------------------------------------------------------------------------
extern "C" void kernel_launch(void* const* d_in, const int* in_sizes, int n_in,
                              void* d_out, int out_size, void* d_ws, size_t ws_size,
                              hipStream_t stream)
{
    const float* x    = (const float*)d_in[0];
    const float* H1_w = (const float*)d_in[1];
    const float* H1_b = (const float*)d_in[2];
    const float* W1_w = (const float*)d_in[3];
    const float* W1_b = (const float*)d_in[4];
    const float* H2_w = (const float*)d_in[5];
    const float* H2_b = (const float*)d_in[6];
    const float* W2_w = (const float*)d_in[7];
    const float* W2_b = (const float*)d_in[8];
    const int*   ei   = (const int*)d_in[9];
    const int*   batch= (const int*)d_in[10];

    const int n_nodes  = in_sizes[0] / AF;   // 50000
    const int n_edges  = in_sizes[9] / 2;    // 1600000
    const int n_graphs = out_size / NFP;     // 2000
    const int* src = ei;
    const int* dst = ei + n_edges;
    float* out = (float*)d_out;

    // workspace layout
    float* bufA    = (float*)d_ws;                          // 3.2M floats
    float* bufB    = bufA + (size_t)n_nodes * AF;           // 3.2M floats
    float* WwT1    = bufB + (size_t)n_nodes * AF;           // 131072
    float* WwT2    = WwT1 + (size_t)AF * NFP;               // 131072
    int*   offsets = (int*)(WwT2 + (size_t)AF * NFP);       // n_nodes+1
    int*   cursor  = offsets + (n_nodes + 1);               // n_nodes+1
    int*   goff    = cursor + (n_nodes + 1);                // n_graphs+1
    int*   esrc    = goff + (n_graphs + 1);                 // n_edges

    const int eb = (n_edges + 255) / 256;
    const int nb = (n_nodes + 255) / 256;
    const int mlp_blocks = (n_nodes + 3) / 4;

    // --- one-time per launch: transposes + CSR + graph offsets ---
    transpose64_kernel<<<NFP / 64, 256, 0, stream>>>(W1_w, WwT1);
    transpose64_kernel<<<NFP / 64, 256, 0, stream>>>(W2_w, WwT2);
    hipMemsetAsync(offsets, 0, (size_t)(n_nodes + 1) * sizeof(int), stream);
    hipMemsetAsync(goff, 0, (size_t)(n_graphs + 1) * sizeof(int), stream);
    hist_kernel<<<eb, 256, 0, stream>>>(dst, offsets, n_edges);
    hist_kernel<<<nb, 256, 0, stream>>>(batch, goff, n_nodes);
    scan_kernel<<<1, 1024, 0, stream>>>(offsets, n_nodes);
    scan_kernel<<<1, 1024, 0, stream>>>(goff, n_graphs);
    hipMemcpyAsync(cursor, offsets, (size_t)n_nodes * sizeof(int),
                   hipMemcpyDeviceToDevice, stream);
    scatter_ids_kernel<<<eb, 256, 0, stream>>>(src, dst, cursor, esrc, n_edges);

    // --- layer 1 ---
    agg_mlp_kernel<<<mlp_blocks, 256, 0, stream>>>(x, offsets, esrc, H1_w, H1_b, bufB, n_nodes);
    fp_pool_graph_kernel<0><<<n_graphs, 256, 0, stream>>>(bufB, WwT1, W1_b, goff, out);

    // --- layer 2 ---
    agg_mlp_kernel<<<mlp_blocks, 256, 0, stream>>>(bufB, offsets, esrc, H2_w, H2_b, bufA, n_nodes);
    fp_pool_graph_kernel<1><<<n_graphs, 256, 0, stream>>>(bufA, WwT2, W2_b, goff, out);
}

// Round 5
// 948.034 us; speedup vs baseline: 7.8131x; 1.1853x over previous
//
#include <hip/hip_runtime.h>
#include <hip/hip_bf16.h>

// N_NODES=50000, N_EDGES=1600000, ATOM_F=64, FP_SIZE=2048, N_GRAPHS=2000
#define AF 64
#define NFP 2048

typedef __attribute__((ext_vector_type(8))) short bf16x8;
typedef __attribute__((ext_vector_type(4))) float f32x4;

__device__ __forceinline__ ushort f2bf(float f) {
    unsigned u = __float_as_uint(f);
    return (ushort)((u + 0x7FFF + ((u >> 16) & 1)) >> 16);   // RNE
}

// ---------------------------------------------------------------------------
// Generic histogram (int32 keys)
// ---------------------------------------------------------------------------
__global__ __launch_bounds__(256) void hist_kernel(
    const int* __restrict__ keys, int* __restrict__ counts, int n)
{
    int e = blockIdx.x * 256 + threadIdx.x;
    if (e < n) atomicAdd(&counts[keys[e]], 1);
}

// single-block exclusive scan, in place; data[n] = total
__global__ __launch_bounds__(1024) void scan_kernel(int* data, int n)
{
    __shared__ int wsum[16];
    __shared__ int chunk_total;
    int t = threadIdx.x, lane = t & 63, w = t >> 6;
    int running = 0;
    for (int base = 0; base < n; base += 1024) {
        int i = base + t;
        int v = (i < n) ? data[i] : 0;
        int x = v;
        #pragma unroll
        for (int off = 1; off < 64; off <<= 1) {
            int y = __shfl_up(x, off);
            if (lane >= off) x += y;
        }
        if (lane == 63) wsum[w] = x;
        __syncthreads();
        if (t == 0) {
            int s = 0;
            #pragma unroll
            for (int q = 0; q < 16; ++q) { int tmp = wsum[q]; wsum[q] = s; s += tmp; }
            chunk_total = s;
        }
        __syncthreads();
        if (i < n) data[i] = x - v + wsum[w] + running;
        running += chunk_total;
        __syncthreads();
    }
    if (t == 0) data[n] = running;
}

__global__ __launch_bounds__(256) void scatter_ids_kernel(
    const int* __restrict__ src, const int* __restrict__ dst,
    int* __restrict__ cursor, int* __restrict__ esrc, int n_edges)
{
    int e = blockIdx.x * 256 + threadIdx.x;
    if (e < n_edges) {
        int pos = atomicAdd(&cursor[dst[e]], 1);
        esrc[pos] = src[e];
    }
}

// ---------------------------------------------------------------------------
// fp32 -> bf16 convert (keeps [2048][64] row-major layout)
// ---------------------------------------------------------------------------
__global__ __launch_bounds__(256) void f2bf_kernel(
    const float* __restrict__ W, ushort* __restrict__ Wbf, int n)
{
    int i = blockIdx.x * 256 + threadIdx.x;
    if (i < n) Wbf[i] = f2bf(W[i]);
}

// ---------------------------------------------------------------------------
// Fused gather-aggregate (CSR, no atomics) + self-loop + 64x64 sigmoid MLP.
// ---------------------------------------------------------------------------
__global__ __launch_bounds__(256) void agg_mlp_kernel(
    const float* __restrict__ h, const int* __restrict__ offsets,
    const int* __restrict__ esrc, const float* __restrict__ Hw,
    const float* __restrict__ Hb, float* __restrict__ out, int n_nodes)
{
    __shared__ float Hw_s[AF * 65];
    __shared__ __align__(16) float part[4][4][AF];
    __shared__ float a_red[4][AF];
    __shared__ float hb_s[AF];

    int t = threadIdx.x;
    for (int idx = t; idx < AF * AF; idx += 256) {
        int j = idx >> 6, k = idx & 63;
        Hw_s[j * 65 + k] = Hw[idx];
    }
    if (t < AF) hb_s[t] = Hb[t];

    int w = t >> 6, lane = t & 63;
    int sub = lane >> 4, f4 = lane & 15;
    int i = blockIdx.x * 4 + w;

    float4 acc = make_float4(0.f, 0.f, 0.f, 0.f);
    if (i < n_nodes) {
        int o0 = offsets[i], o1 = offsets[i + 1];
        const int* ep = esrc + o0;
        int deg = o1 - o0;
        const float4* h4 = (const float4*)h;
        int j = 0;
        for (; j + 4 <= deg; j += 4) {
            int s = ep[j + sub];
            float4 v = h4[(size_t)s * 16 + f4];
            acc.x += v.x; acc.y += v.y; acc.z += v.z; acc.w += v.w;
        }
        if (j + sub < deg) {
            int s = ep[j + sub];
            float4 v = h4[(size_t)s * 16 + f4];
            acc.x += v.x; acc.y += v.y; acc.z += v.z; acc.w += v.w;
        }
    }
    *(float4*)&part[w][sub][f4 * 4] = acc;
    __syncthreads();

    if (i < n_nodes) {
        float val = h[(size_t)i * AF + lane]
                  + part[w][0][lane] + part[w][1][lane]
                  + part[w][2][lane] + part[w][3][lane];
        a_red[w][lane] = val;
    }
    __syncthreads();

    if (i < n_nodes) {
        float z = hb_s[lane];
        #pragma unroll
        for (int k = 0; k < AF; ++k)
            z = fmaf(a_red[w][k], Hw_s[lane * 65 + k], z);
        out[(size_t)i * AF + lane] = 1.f / (1.f + __expf(-z));
    }
}

// ---------------------------------------------------------------------------
// Fingerprint via MFMA (16x16x32 bf16) + softmax + pooling.
// One block (512 thr = 8 waves) per graph; 16-node chunks.
//  A: upd chunk -> bf16, XOR-swizzled LDS [16 nodes][64 k].
//  B: Wbf [2048][64] bf16 streamed global->reg (contiguous 16B per lane).
//  z: 16 f32x4 per lane (wave owns 256 cols), fully static indexing.
//  D layout (verified): col = lane&15, node = (lane>>4)*4 + reg.
// ---------------------------------------------------------------------------
template <int ACCUM>
__global__ __launch_bounds__(512, 4) void fp_pool_graph_kernel(
    const float* __restrict__ upd, const ushort* __restrict__ Wbf,
    const float* __restrict__ Wb, const int* __restrict__ goff,
    float* __restrict__ out)
{
    __shared__ ushort upd_s[16 * 64];          // 2 KB, swizzled rows
    __shared__ __align__(16) float facc[NFP];  // 8 KB
    __shared__ __align__(16) float wb_s[NFP];  // 8 KB
    __shared__ __align__(16) float red_m[4][4][8];  // [G][r][wave]
    __shared__ __align__(16) float red_s[4][4][8];

    int t = threadIdx.x;
    int wave = t >> 6, lane = t & 63;
    int G = lane >> 4, sl = lane & 15;
    int g = blockIdx.x;
    int gs = goff[g], ge = goff[g + 1];

    #pragma unroll
    for (int r = 0; r < 4; ++r) facc[t + r * 512] = 0.f;
    *(float4*)&wb_s[t * 4] = *(const float4*)&Wb[t * 4];

    for (int i0 = gs; i0 < ge; i0 += 16) {
        int nvalid = ge - i0;                  // block-uniform
        if (nvalid > 16) nvalid = 16;

        __syncthreads();   // upd_s free (also covers facc/wb init on iter 0)
        if (t < 256) {
            int node = t >> 4, q = t & 15;
            float4 v = make_float4(0.f, 0.f, 0.f, 0.f);
            if (node < nvalid) v = *(const float4*)&upd[(size_t)(i0 + node) * AF + q * 4];
            ushort4 b;
            b.x = f2bf(v.x); b.y = f2bf(v.y); b.z = f2bf(v.z); b.w = f2bf(v.w);
            int byteoff = node * 128 + ((q * 8) ^ ((node & 7) << 4));
            *(ushort4*)((char*)upd_s + byteoff) = b;
        }
        __syncthreads();

        // A fragments: lane reads node-row (sl), k = G*8.. and +32
        int row = sl;
        int swz = (row & 7) << 4;
        bf16x8 a0 = *(bf16x8*)((char*)upd_s + row * 128 + ((G * 16) ^ swz));
        bf16x8 a1 = *(bf16x8*)((char*)upd_s + row * 128 + ((G * 16 + 64) ^ swz));

        f32x4 z[16];
        #pragma unroll
        for (int ct = 0; ct < 16; ++ct) {
            int col = wave * 256 + ct * 16 + sl;
            const ushort* wp = Wbf + (size_t)col * AF + G * 8;
            bf16x8 b0 = *(const bf16x8*)wp;
            bf16x8 b1 = *(const bf16x8*)(wp + 32);
            f32x4 d = {0.f, 0.f, 0.f, 0.f};
            d = __builtin_amdgcn_mfma_f32_16x16x32_bf16(a0, b0, d, 0, 0, 0);
            d = __builtin_amdgcn_mfma_f32_16x16x32_bf16(a1, b1, d, 0, 0, 0);
            float bias = wb_s[col];
            d[0] += bias; d[1] += bias; d[2] += bias; d[3] += bias;
            z[ct] = d;
        }

        // ---- per-node max: lane holds nodes 4G+r ----
        float mp[4] = {-1e30f, -1e30f, -1e30f, -1e30f};
        #pragma unroll
        for (int ct = 0; ct < 16; ++ct)
            #pragma unroll
            for (int r = 0; r < 4; ++r) mp[r] = fmaxf(mp[r], z[ct][r]);
        #pragma unroll
        for (int mask = 1; mask <= 8; mask <<= 1)
            #pragma unroll
            for (int r = 0; r < 4; ++r) mp[r] = fmaxf(mp[r], __shfl_xor(mp[r], mask));
        if (sl == 0) {
            #pragma unroll
            for (int r = 0; r < 4; ++r) red_m[G][r][wave] = mp[r];
        }
        __syncthreads();
        float mf[4];
        #pragma unroll
        for (int r = 0; r < 4; ++r) {
            float4 u = *(float4*)&red_m[G][r][0];
            float4 v = *(float4*)&red_m[G][r][4];
            mf[r] = fmaxf(fmaxf(fmaxf(u.x, u.y), fmaxf(u.z, u.w)),
                          fmaxf(fmaxf(v.x, v.y), fmaxf(v.z, v.w)));
        }

        // ---- exp (in place) + per-node sum ----
        float sp[4] = {0.f, 0.f, 0.f, 0.f};
        #pragma unroll
        for (int ct = 0; ct < 16; ++ct)
            #pragma unroll
            for (int r = 0; r < 4; ++r) {
                float e = __expf(z[ct][r] - mf[r]);
                z[ct][r] = e;
                sp[r] += e;
            }
        #pragma unroll
        for (int mask = 1; mask <= 8; mask <<= 1)
            #pragma unroll
            for (int r = 0; r < 4; ++r) sp[r] += __shfl_xor(sp[r], mask);
        if (sl == 0) {
            #pragma unroll
            for (int r = 0; r < 4; ++r) red_s[G][r][wave] = sp[r];
        }
        __syncthreads();
        float sc[4];
        #pragma unroll
        for (int r = 0; r < 4; ++r) {
            float4 u = *(float4*)&red_s[G][r][0];
            float4 v = *(float4*)&red_s[G][r][4];
            float sf = u.x + u.y + u.z + u.w + v.x + v.y + v.z + v.w;
            int nd = G * 4 + r;
            sc[r] = (nd < nvalid) ? 1.f / sf : 0.f;
        }

        // ---- pool: per column, sum over 16 nodes, add into facc ----
        #pragma unroll
        for (int ct = 0; ct < 16; ++ct) {
            float c = z[ct][0] * sc[0] + z[ct][1] * sc[1]
                    + z[ct][2] * sc[2] + z[ct][3] * sc[3];
            c += __shfl_xor(c, 16);
            c += __shfl_xor(c, 32);
            if (G == 0) {
                int col = wave * 256 + ct * 16 + sl;
                facc[col] += c;     // exclusive (wave,ct,sl) -> col
            }
        }
    }

    __syncthreads();
    float4 fa = *(float4*)&facc[t * 4];
    float* po = &out[(size_t)g * NFP];
    if (ACCUM) {
        float4 oa = *(const float4*)&po[t * 4];
        fa.x += oa.x; fa.y += oa.y; fa.z += oa.z; fa.w += oa.w;
    }
    *(float4*)&po[t * 4] = fa;
}

// ---------------------------------------------------------------------------
extern "C" void kernel_launch(void* const* d_in, const int* in_sizes, int n_in,
                              void* d_out, int out_size, void* d_ws, size_t ws_size,
                              hipStream_t stream)
{
    const float* x    = (const float*)d_in[0];
    const float* H1_w = (const float*)d_in[1];
    const float* H1_b = (const float*)d_in[2];
    const float* W1_w = (const float*)d_in[3];
    const float* W1_b = (const float*)d_in[4];
    const float* H2_w = (const float*)d_in[5];
    const float* H2_b = (const float*)d_in[6];
    const float* W2_w = (const float*)d_in[7];
    const float* W2_b = (const float*)d_in[8];
    const int*   ei   = (const int*)d_in[9];
    const int*   batch= (const int*)d_in[10];

    const int n_nodes  = in_sizes[0] / AF;   // 50000
    const int n_edges  = in_sizes[9] / 2;    // 1600000
    const int n_graphs = out_size / NFP;     // 2000
    const int* src = ei;
    const int* dst = ei + n_edges;
    float* out = (float*)d_out;

    // workspace layout
    float*  bufA    = (float*)d_ws;                         // 3.2M floats
    float*  bufB    = bufA + (size_t)n_nodes * AF;          // 3.2M floats
    ushort* Wbf1    = (ushort*)(bufB + (size_t)n_nodes * AF);  // 131072 ushort
    ushort* Wbf2    = Wbf1 + (size_t)NFP * AF;                 // 131072 ushort
    int*    offsets = (int*)(Wbf2 + (size_t)NFP * AF);      // n_nodes+1
    int*    cursor  = offsets + (n_nodes + 1);              // n_nodes+1
    int*    goff    = cursor + (n_nodes + 1);               // n_graphs+1
    int*    esrc    = goff + (n_graphs + 1);                // n_edges

    const int eb = (n_edges + 255) / 256;
    const int nb = (n_nodes + 255) / 256;
    const int mlp_blocks = (n_nodes + 3) / 4;
    const int wn = NFP * AF;                 // 131072

    // --- one-time per launch: bf16 weights + CSR + graph offsets ---
    f2bf_kernel<<<(wn + 255) / 256, 256, 0, stream>>>(W1_w, Wbf1, wn);
    f2bf_kernel<<<(wn + 255) / 256, 256, 0, stream>>>(W2_w, Wbf2, wn);
    hipMemsetAsync(offsets, 0, (size_t)(n_nodes + 1) * sizeof(int), stream);
    hipMemsetAsync(goff, 0, (size_t)(n_graphs + 1) * sizeof(int), stream);
    hist_kernel<<<eb, 256, 0, stream>>>(dst, offsets, n_edges);
    hist_kernel<<<nb, 256, 0, stream>>>(batch, goff, n_nodes);
    scan_kernel<<<1, 1024, 0, stream>>>(offsets, n_nodes);
    scan_kernel<<<1, 1024, 0, stream>>>(goff, n_graphs);
    hipMemcpyAsync(cursor, offsets, (size_t)n_nodes * sizeof(int),
                   hipMemcpyDeviceToDevice, stream);
    scatter_ids_kernel<<<eb, 256, 0, stream>>>(src, dst, cursor, esrc, n_edges);

    // --- layer 1 ---
    agg_mlp_kernel<<<mlp_blocks, 256, 0, stream>>>(x, offsets, esrc, H1_w, H1_b, bufB, n_nodes);
    fp_pool_graph_kernel<0><<<n_graphs, 512, 0, stream>>>(bufB, Wbf1, W1_b, goff, out);

    // --- layer 2 ---
    agg_mlp_kernel<<<mlp_blocks, 256, 0, stream>>>(bufB, offsets, esrc, H2_w, H2_b, bufA, n_nodes);
    fp_pool_graph_kernel<1><<<n_graphs, 512, 0, stream>>>(bufA, Wbf2, W2_b, goff, out);
}

// Round 6
// 895.822 us; speedup vs baseline: 8.2685x; 1.0583x over previous
//
#include <hip/hip_runtime.h>
#include <hip/hip_bf16.h>

// N_NODES=50000, N_EDGES=1600000, ATOM_F=64, FP_SIZE=2048, N_GRAPHS=2000
#define AF 64
#define NFP 2048

typedef __attribute__((ext_vector_type(8))) short bf16x8;
typedef __attribute__((ext_vector_type(4))) float f32x4;

__device__ __forceinline__ ushort f2bf(float f) {
    unsigned u = __float_as_uint(f);
    return (ushort)((u + 0x7FFF + ((u >> 16) & 1)) >> 16);   // RNE
}

// ---------------------------------------------------------------------------
// Generic histogram (int32 keys)
// ---------------------------------------------------------------------------
__global__ __launch_bounds__(256) void hist_kernel(
    const int* __restrict__ keys, int* __restrict__ counts, int n)
{
    int e = blockIdx.x * 256 + threadIdx.x;
    if (e < n) atomicAdd(&counts[keys[e]], 1);
}

// single-block exclusive scan, in place; data[n] = total
__global__ __launch_bounds__(1024) void scan_kernel(int* data, int n)
{
    __shared__ int wsum[16];
    __shared__ int chunk_total;
    int t = threadIdx.x, lane = t & 63, w = t >> 6;
    int running = 0;
    for (int base = 0; base < n; base += 1024) {
        int i = base + t;
        int v = (i < n) ? data[i] : 0;
        int x = v;
        #pragma unroll
        for (int off = 1; off < 64; off <<= 1) {
            int y = __shfl_up(x, off);
            if (lane >= off) x += y;
        }
        if (lane == 63) wsum[w] = x;
        __syncthreads();
        if (t == 0) {
            int s = 0;
            #pragma unroll
            for (int q = 0; q < 16; ++q) { int tmp = wsum[q]; wsum[q] = s; s += tmp; }
            chunk_total = s;
        }
        __syncthreads();
        if (i < n) data[i] = x - v + wsum[w] + running;
        running += chunk_total;
        __syncthreads();
    }
    if (t == 0) data[n] = running;
}

__global__ __launch_bounds__(256) void scatter_ids_kernel(
    const int* __restrict__ src, const int* __restrict__ dst,
    int* __restrict__ cursor, int* __restrict__ esrc, int n_edges)
{
    int e = blockIdx.x * 256 + threadIdx.x;
    if (e < n_edges) {
        int pos = atomicAdd(&cursor[dst[e]], 1);
        esrc[pos] = src[e];
    }
}

// ---------------------------------------------------------------------------
// fp32 -> bf16 convert (keeps [2048][64] row-major layout)
// ---------------------------------------------------------------------------
__global__ __launch_bounds__(256) void f2bf_kernel(
    const float* __restrict__ W, ushort* __restrict__ Wbf, int n)
{
    int i = blockIdx.x * 256 + threadIdx.x;
    if (i < n) Wbf[i] = f2bf(W[i]);
}

// ---------------------------------------------------------------------------
// Fused gather-aggregate (CSR, no atomics) + self-loop + 64x64 sigmoid MLP.
// ---------------------------------------------------------------------------
__global__ __launch_bounds__(256) void agg_mlp_kernel(
    const float* __restrict__ h, const int* __restrict__ offsets,
    const int* __restrict__ esrc, const float* __restrict__ Hw,
    const float* __restrict__ Hb, float* __restrict__ out, int n_nodes)
{
    __shared__ float Hw_s[AF * 65];
    __shared__ __align__(16) float part[4][4][AF];
    __shared__ float a_red[4][AF];
    __shared__ float hb_s[AF];

    int t = threadIdx.x;
    for (int idx = t; idx < AF * AF; idx += 256) {
        int j = idx >> 6, k = idx & 63;
        Hw_s[j * 65 + k] = Hw[idx];
    }
    if (t < AF) hb_s[t] = Hb[t];

    int w = t >> 6, lane = t & 63;
    int sub = lane >> 4, f4 = lane & 15;
    int i = blockIdx.x * 4 + w;

    float4 acc = make_float4(0.f, 0.f, 0.f, 0.f);
    if (i < n_nodes) {
        int o0 = offsets[i], o1 = offsets[i + 1];
        const int* ep = esrc + o0;
        int deg = o1 - o0;
        const float4* h4 = (const float4*)h;
        int j = 0;
        for (; j + 4 <= deg; j += 4) {
            int s = ep[j + sub];
            float4 v = h4[(size_t)s * 16 + f4];
            acc.x += v.x; acc.y += v.y; acc.z += v.z; acc.w += v.w;
        }
        if (j + sub < deg) {
            int s = ep[j + sub];
            float4 v = h4[(size_t)s * 16 + f4];
            acc.x += v.x; acc.y += v.y; acc.z += v.z; acc.w += v.w;
        }
    }
    *(float4*)&part[w][sub][f4 * 4] = acc;
    __syncthreads();

    if (i < n_nodes) {
        float val = h[(size_t)i * AF + lane]
                  + part[w][0][lane] + part[w][1][lane]
                  + part[w][2][lane] + part[w][3][lane];
        a_red[w][lane] = val;
    }
    __syncthreads();

    if (i < n_nodes) {
        float z = hb_s[lane];
        #pragma unroll
        for (int k = 0; k < AF; ++k)
            z = fmaf(a_red[w][k], Hw_s[lane * 65 + k], z);
        out[(size_t)i * AF + lane] = 1.f / (1.f + __expf(-z));
    }
}

// ---------------------------------------------------------------------------
// Fingerprint via MFMA + TWO-PASS online softmax + pooling (no z storage,
// no spills). One block (512 thr = 8 waves) per graph; 16-node chunks.
// Pass A: stream B tiles, track running (max,sum) per node — 8 regs/lane.
// Pass B: recompute tiles (MFMA ~idle anyway), accumulate exp/s into facc.
//  D layout (verified): col = lane&15, node = (lane>>4)*4 + reg.
// ---------------------------------------------------------------------------
template <int ACCUM>
__global__ __launch_bounds__(512, 4) void fp_pool_graph_kernel(
    const float* __restrict__ upd, const ushort* __restrict__ Wbf,
    const float* __restrict__ Wb, const int* __restrict__ goff,
    float* __restrict__ out)
{
    __shared__ ushort upd_s[16 * 64];          // 2 KB, swizzled rows
    __shared__ __align__(16) float facc[NFP];  // 8 KB
    __shared__ __align__(16) float wb_s[NFP];  // 8 KB
    __shared__ float red_m[4][4][8];           // [G][r][wave]
    __shared__ float red_s[4][4][8];

    int t = threadIdx.x;
    int wave = t >> 6, lane = t & 63;
    int G = lane >> 4, sl = lane & 15;
    int g = blockIdx.x;
    int gs = goff[g], ge = goff[g + 1];

    #pragma unroll
    for (int r = 0; r < 4; ++r) facc[t + r * 512] = 0.f;
    *(float4*)&wb_s[t * 4] = *(const float4*)&Wb[t * 4];

    for (int i0 = gs; i0 < ge; i0 += 16) {
        int nvalid = ge - i0;                  // block-uniform
        if (nvalid > 16) nvalid = 16;

        __syncthreads();   // upd_s free (also covers facc/wb init on iter 0)
        if (t < 256) {
            int node = t >> 4, q = t & 15;
            float4 v = make_float4(0.f, 0.f, 0.f, 0.f);
            if (node < nvalid) v = *(const float4*)&upd[(size_t)(i0 + node) * AF + q * 4];
            ushort4 b;
            b.x = f2bf(v.x); b.y = f2bf(v.y); b.z = f2bf(v.z); b.w = f2bf(v.w);
            int byteoff = node * 128 + ((q * 8) ^ ((node & 7) << 4));
            *(ushort4*)((char*)upd_s + byteoff) = b;
        }
        __syncthreads();

        // A fragments: lane reads node-row (sl), k = G*8.. and +32
        int row = sl;
        int swz = (row & 7) << 4;
        bf16x8 a0 = *(bf16x8*)((char*)upd_s + row * 128 + ((G * 16) ^ swz));
        bf16x8 a1 = *(bf16x8*)((char*)upd_s + row * 128 + ((G * 16 + 64) ^ swz));

        // ---- pass A: online (max, sum) per node, no z storage ----
        float m[4] = {-1e30f, -1e30f, -1e30f, -1e30f};
        float s[4] = {0.f, 0.f, 0.f, 0.f};
        #pragma unroll
        for (int ct = 0; ct < 16; ++ct) {
            int col = wave * 256 + ct * 16 + sl;
            const ushort* wp = Wbf + (size_t)col * AF + G * 8;
            bf16x8 b0 = *(const bf16x8*)wp;
            bf16x8 b1 = *(const bf16x8*)(wp + 32);
            f32x4 d = {0.f, 0.f, 0.f, 0.f};
            d = __builtin_amdgcn_mfma_f32_16x16x32_bf16(a0, b0, d, 0, 0, 0);
            d = __builtin_amdgcn_mfma_f32_16x16x32_bf16(a1, b1, d, 0, 0, 0);
            float bias = wb_s[col];
            #pragma unroll
            for (int r = 0; r < 4; ++r) {
                float v = d[r] + bias;
                float mn = fmaxf(m[r], v);
                s[r] = s[r] * __expf(m[r] - mn) + __expf(v - mn);
                m[r] = mn;
            }
        }
        // merge across the 16 lanes of group G (masks 1,2,4,8 stay in-group)
        #pragma unroll
        for (int mask = 1; mask <= 8; mask <<= 1) {
            #pragma unroll
            for (int r = 0; r < 4; ++r) {
                float mo = __shfl_xor(m[r], mask);
                float so = __shfl_xor(s[r], mask);
                float mn = fmaxf(m[r], mo);
                s[r] = s[r] * __expf(m[r] - mn) + so * __expf(mo - mn);
                m[r] = mn;
            }
        }
        if (sl == 0) {
            #pragma unroll
            for (int r = 0; r < 4; ++r) {
                red_m[G][r][wave] = m[r];
                red_s[G][r][wave] = s[r];
            }
        }
        __syncthreads();
        float mf[4], sc[4];
        #pragma unroll
        for (int r = 0; r < 4; ++r) {
            float M = -1e30f, S = 0.f;
            #pragma unroll
            for (int w8 = 0; w8 < 8; ++w8) {
                float mo = red_m[G][r][w8];
                float so = red_s[G][r][w8];
                float mn = fmaxf(M, mo);
                S = S * __expf(M - mn) + so * __expf(mo - mn);
                M = mn;
            }
            mf[r] = M;
            int nd = G * 4 + r;
            sc[r] = (nd < nvalid) ? 1.f / S : 0.f;
        }

        // ---- pass B: recompute tiles, pool into facc ----
        #pragma unroll
        for (int ct = 0; ct < 16; ++ct) {
            int col = wave * 256 + ct * 16 + sl;
            const ushort* wp = Wbf + (size_t)col * AF + G * 8;
            bf16x8 b0 = *(const bf16x8*)wp;
            bf16x8 b1 = *(const bf16x8*)(wp + 32);
            f32x4 d = {0.f, 0.f, 0.f, 0.f};
            d = __builtin_amdgcn_mfma_f32_16x16x32_bf16(a0, b0, d, 0, 0, 0);
            d = __builtin_amdgcn_mfma_f32_16x16x32_bf16(a1, b1, d, 0, 0, 0);
            float bias = wb_s[col];
            float c = __expf(d[0] + bias - mf[0]) * sc[0]
                    + __expf(d[1] + bias - mf[1]) * sc[1]
                    + __expf(d[2] + bias - mf[2]) * sc[2]
                    + __expf(d[3] + bias - mf[3]) * sc[3];
            c += __shfl_xor(c, 16);
            c += __shfl_xor(c, 32);
            if (G == 0) facc[col] += c;   // exclusive (wave,ct,sl) -> col
        }
    }

    __syncthreads();
    float4 fa = *(float4*)&facc[t * 4];
    float* po = &out[(size_t)g * NFP];
    if (ACCUM) {
        float4 oa = *(const float4*)&po[t * 4];
        fa.x += oa.x; fa.y += oa.y; fa.z += oa.z; fa.w += oa.w;
    }
    *(float4*)&po[t * 4] = fa;
}

// ---------------------------------------------------------------------------
extern "C" void kernel_launch(void* const* d_in, const int* in_sizes, int n_in,
                              void* d_out, int out_size, void* d_ws, size_t ws_size,
                              hipStream_t stream)
{
    const float* x    = (const float*)d_in[0];
    const float* H1_w = (const float*)d_in[1];
    const float* H1_b = (const float*)d_in[2];
    const float* W1_w = (const float*)d_in[3];
    const float* W1_b = (const float*)d_in[4];
    const float* H2_w = (const float*)d_in[5];
    const float* H2_b = (const float*)d_in[6];
    const float* W2_w = (const float*)d_in[7];
    const float* W2_b = (const float*)d_in[8];
    const int*   ei   = (const int*)d_in[9];
    const int*   batch= (const int*)d_in[10];

    const int n_nodes  = in_sizes[0] / AF;   // 50000
    const int n_edges  = in_sizes[9] / 2;    // 1600000
    const int n_graphs = out_size / NFP;     // 2000
    const int* src = ei;
    const int* dst = ei + n_edges;
    float* out = (float*)d_out;

    // workspace layout
    float*  bufA    = (float*)d_ws;                         // 3.2M floats
    float*  bufB    = bufA + (size_t)n_nodes * AF;          // 3.2M floats
    ushort* Wbf1    = (ushort*)(bufB + (size_t)n_nodes * AF);  // 131072 ushort
    ushort* Wbf2    = Wbf1 + (size_t)NFP * AF;                 // 131072 ushort
    int*    offsets = (int*)(Wbf2 + (size_t)NFP * AF);      // n_nodes+1
    int*    cursor  = offsets + (n_nodes + 1);              // n_nodes+1
    int*    goff    = cursor + (n_nodes + 1);               // n_graphs+1
    int*    esrc    = goff + (n_graphs + 1);                // n_edges

    const int eb = (n_edges + 255) / 256;
    const int nb = (n_nodes + 255) / 256;
    const int mlp_blocks = (n_nodes + 3) / 4;
    const int wn = NFP * AF;                 // 131072

    // --- one-time per launch: bf16 weights + CSR + graph offsets ---
    f2bf_kernel<<<(wn + 255) / 256, 256, 0, stream>>>(W1_w, Wbf1, wn);
    f2bf_kernel<<<(wn + 255) / 256, 256, 0, stream>>>(W2_w, Wbf2, wn);
    hipMemsetAsync(offsets, 0, (size_t)(n_nodes + 1) * sizeof(int), stream);
    hipMemsetAsync(goff, 0, (size_t)(n_graphs + 1) * sizeof(int), stream);
    hist_kernel<<<eb, 256, 0, stream>>>(dst, offsets, n_edges);
    hist_kernel<<<nb, 256, 0, stream>>>(batch, goff, n_nodes);
    scan_kernel<<<1, 1024, 0, stream>>>(offsets, n_nodes);
    scan_kernel<<<1, 1024, 0, stream>>>(goff, n_graphs);
    hipMemcpyAsync(cursor, offsets, (size_t)n_nodes * sizeof(int),
                   hipMemcpyDeviceToDevice, stream);
    scatter_ids_kernel<<<eb, 256, 0, stream>>>(src, dst, cursor, esrc, n_edges);

    // --- layer 1 ---
    agg_mlp_kernel<<<mlp_blocks, 256, 0, stream>>>(x, offsets, esrc, H1_w, H1_b, bufB, n_nodes);
    fp_pool_graph_kernel<0><<<n_graphs, 512, 0, stream>>>(bufB, Wbf1, W1_b, goff, out);

    // --- layer 2 ---
    agg_mlp_kernel<<<mlp_blocks, 256, 0, stream>>>(bufB, offsets, esrc, H2_w, H2_b, bufA, n_nodes);
    fp_pool_graph_kernel<1><<<n_graphs, 512, 0, stream>>>(bufA, Wbf2, W2_b, goff, out);
}

// Round 7
// 740.398 us; speedup vs baseline: 10.0042x; 1.2099x over previous
//
#include <hip/hip_runtime.h>
#include <hip/hip_bf16.h>

// N_NODES=50000, N_EDGES=1600000, ATOM_F=64, FP_SIZE=2048, N_GRAPHS=2000
#define AF 64
#define NFP 2048

typedef __attribute__((ext_vector_type(8))) short bf16x8;
typedef __attribute__((ext_vector_type(4))) float f32x4;

__device__ __forceinline__ ushort f2bf(float f) {
    unsigned u = __float_as_uint(f);
    return (ushort)((u + 0x7FFF + ((u >> 16) & 1)) >> 16);   // RNE
}

// ---------------------------------------------------------------------------
// Generic histogram (int32 keys)
// ---------------------------------------------------------------------------
__global__ __launch_bounds__(256) void hist_kernel(
    const int* __restrict__ keys, int* __restrict__ counts, int n)
{
    int e = blockIdx.x * 256 + threadIdx.x;
    if (e < n) atomicAdd(&counts[keys[e]], 1);
}

// single-block exclusive scan, in place; data[n] = total
__global__ __launch_bounds__(1024) void scan_kernel(int* data, int n)
{
    __shared__ int wsum[16];
    __shared__ int chunk_total;
    int t = threadIdx.x, lane = t & 63, w = t >> 6;
    int running = 0;
    for (int base = 0; base < n; base += 1024) {
        int i = base + t;
        int v = (i < n) ? data[i] : 0;
        int x = v;
        #pragma unroll
        for (int off = 1; off < 64; off <<= 1) {
            int y = __shfl_up(x, off);
            if (lane >= off) x += y;
        }
        if (lane == 63) wsum[w] = x;
        __syncthreads();
        if (t == 0) {
            int s = 0;
            #pragma unroll
            for (int q = 0; q < 16; ++q) { int tmp = wsum[q]; wsum[q] = s; s += tmp; }
            chunk_total = s;
        }
        __syncthreads();
        if (i < n) data[i] = x - v + wsum[w] + running;
        running += chunk_total;
        __syncthreads();
    }
    if (t == 0) data[n] = running;
}

__global__ __launch_bounds__(256) void scatter_ids_kernel(
    const int* __restrict__ src, const int* __restrict__ dst,
    int* __restrict__ cursor, int* __restrict__ esrc, int n_edges)
{
    int e = blockIdx.x * 256 + threadIdx.x;
    if (e < n_edges) {
        int pos = atomicAdd(&cursor[dst[e]], 1);
        esrc[pos] = src[e];
    }
}

// ---------------------------------------------------------------------------
// fp32 -> bf16 convert
// ---------------------------------------------------------------------------
__global__ __launch_bounds__(256) void f2bf_kernel(
    const float* __restrict__ W, ushort* __restrict__ Wbf, int n)
{
    int i = blockIdx.x * 256 + threadIdx.x;
    if (i < n) Wbf[i] = f2bf(W[i]);
}

// ---------------------------------------------------------------------------
// Fused gather-aggregate (CSR, no atomics) + self-loop + 64x64 sigmoid MLP.
// Emits BOTH fp32 (for next layer's fp32 gather) and bf16 (for MFMA kernels).
// ---------------------------------------------------------------------------
__global__ __launch_bounds__(256) void agg_mlp_kernel(
    const float* __restrict__ h, const int* __restrict__ offsets,
    const int* __restrict__ esrc, const float* __restrict__ Hw,
    const float* __restrict__ Hb, float* __restrict__ out,
    ushort* __restrict__ outbf, int n_nodes)
{
    __shared__ float Hw_s[AF * 65];
    __shared__ __align__(16) float part[4][4][AF];
    __shared__ float a_red[4][AF];
    __shared__ float hb_s[AF];

    int t = threadIdx.x;
    for (int idx = t; idx < AF * AF; idx += 256) {
        int j = idx >> 6, k = idx & 63;
        Hw_s[j * 65 + k] = Hw[idx];
    }
    if (t < AF) hb_s[t] = Hb[t];

    int w = t >> 6, lane = t & 63;
    int sub = lane >> 4, f4 = lane & 15;
    int i = blockIdx.x * 4 + w;

    float4 acc = make_float4(0.f, 0.f, 0.f, 0.f);
    if (i < n_nodes) {
        int o0 = offsets[i], o1 = offsets[i + 1];
        const int* ep = esrc + o0;
        int deg = o1 - o0;
        const float4* h4 = (const float4*)h;
        int j = 0;
        for (; j + 4 <= deg; j += 4) {
            int s = ep[j + sub];
            float4 v = h4[(size_t)s * 16 + f4];
            acc.x += v.x; acc.y += v.y; acc.z += v.z; acc.w += v.w;
        }
        if (j + sub < deg) {
            int s = ep[j + sub];
            float4 v = h4[(size_t)s * 16 + f4];
            acc.x += v.x; acc.y += v.y; acc.z += v.z; acc.w += v.w;
        }
    }
    *(float4*)&part[w][sub][f4 * 4] = acc;
    __syncthreads();

    if (i < n_nodes) {
        float val = h[(size_t)i * AF + lane]
                  + part[w][0][lane] + part[w][1][lane]
                  + part[w][2][lane] + part[w][3][lane];
        a_red[w][lane] = val;
    }
    __syncthreads();

    if (i < n_nodes) {
        float z = hb_s[lane];
        #pragma unroll
        for (int k = 0; k < AF; ++k)
            z = fmaf(a_red[w][k], Hw_s[lane * 65 + k], z);
        float sg = 1.f / (1.f + __expf(-z));
        out[(size_t)i * AF + lane] = sg;
        outbf[(size_t)i * AF + lane] = f2bf(sg);
    }
}

// ---------------------------------------------------------------------------
// Softmax denominators: sden[n] = 1 / sum_j exp(z_nj), z = upd @ Ww^T + Wb.
// No max subtraction: upd in (0,1), ||W_row|| ~ 1  =>  |z| < ~10, exp safe.
// Block 256 thr = 4 waves; each wave owns 32 contiguous nodes (2 MFMA row
// tiles held in 4 A-fragments loaded DIRECTLY from global updbf — lane
// layout (row=sl, kchunk=G) IS the MFMA A layout; fully coalesced).
// Streams all 2048 cols; only 8 persistent accum regs per lane.
// ---------------------------------------------------------------------------
__global__ __launch_bounds__(256) void denom_kernel(
    const ushort* __restrict__ updbf, const ushort* __restrict__ Wbf,
    const float* __restrict__ Wb, float* __restrict__ sden, int n_nodes)
{
    __shared__ float wb_s[NFP];
    int t = threadIdx.x, wave = t >> 6, lane = t & 63;
    int G = lane >> 4, sl = lane & 15;
    for (int i = t; i < NFP / 4; i += 256)
        *(float4*)&wb_s[i * 4] = *(const float4*)&Wb[i * 4];
    __syncthreads();

    int base = blockIdx.x * 128 + wave * 32;     // updbf padded past n_nodes
    bf16x8 a00, a01, a10, a11;
    {
        const ushort* p0 = updbf + (size_t)(base + sl) * AF + G * 8;
        a00 = *(const bf16x8*)p0;
        a01 = *(const bf16x8*)(p0 + 32);
        const ushort* p1 = updbf + (size_t)(base + 16 + sl) * AF + G * 8;
        a10 = *(const bf16x8*)p1;
        a11 = *(const bf16x8*)(p1 + 32);
    }
    float s0[4] = {0.f, 0.f, 0.f, 0.f};
    float s1[4] = {0.f, 0.f, 0.f, 0.f};

    #pragma unroll 2
    for (int ct = 0; ct < 128; ++ct) {
        int col = ct * 16 + sl;
        const ushort* wp = Wbf + (size_t)col * AF + G * 8;
        bf16x8 b0 = *(const bf16x8*)wp;
        bf16x8 b1 = *(const bf16x8*)(wp + 32);
        float bias = wb_s[col];
        f32x4 d0 = {0.f, 0.f, 0.f, 0.f};
        d0 = __builtin_amdgcn_mfma_f32_16x16x32_bf16(a00, b0, d0, 0, 0, 0);
        d0 = __builtin_amdgcn_mfma_f32_16x16x32_bf16(a01, b1, d0, 0, 0, 0);
        f32x4 d1 = {0.f, 0.f, 0.f, 0.f};
        d1 = __builtin_amdgcn_mfma_f32_16x16x32_bf16(a10, b0, d1, 0, 0, 0);
        d1 = __builtin_amdgcn_mfma_f32_16x16x32_bf16(a11, b1, d1, 0, 0, 0);
        #pragma unroll
        for (int r = 0; r < 4; ++r) {
            s0[r] += __expf(d0[r] + bias);
            s1[r] += __expf(d1[r] + bias);
        }
    }
    #pragma unroll
    for (int mask = 1; mask <= 8; mask <<= 1) {
        #pragma unroll
        for (int r = 0; r < 4; ++r) {
            s0[r] += __shfl_xor(s0[r], mask);
            s1[r] += __shfl_xor(s1[r], mask);
        }
    }
    if (sl == 0) {
        #pragma unroll
        for (int r = 0; r < 4; ++r) {
            int n0 = base + G * 4 + r;           // D row = G*4 + r
            if (n0 < n_nodes) sden[n0] = 1.f / s0[r];
            int n1 = n0 + 16;
            if (n1 < n_nodes) sden[n1] = 1.f / s1[r];
        }
    }
}

// ---------------------------------------------------------------------------
// Fingerprint pooling with precomputed denominators: one block per graph,
// out[g][j] = sum_{n in g} exp(z_nj) * sden[n].  No block reductions, no
// barriers in the main loop, no z storage.  Wave owns 256 cols of facc
// exclusively (init + update); M=32 node chunks; A-frags direct from global.
// ---------------------------------------------------------------------------
template <int ACCUM>
__global__ __launch_bounds__(512) void fp_pool_graph_kernel(
    const ushort* __restrict__ updbf, const ushort* __restrict__ Wbf,
    const float* __restrict__ Wb, const float* __restrict__ sden,
    const int* __restrict__ goff, float* __restrict__ out)
{
    __shared__ __align__(16) float facc[NFP];
    __shared__ __align__(16) float wb_s[NFP];

    int t = threadIdx.x, wave = t >> 6, lane = t & 63;
    int G = lane >> 4, sl = lane & 15;
    int c0 = wave * 256;

    *(float4*)&facc[c0 + lane * 4] = make_float4(0.f, 0.f, 0.f, 0.f);
    *(float4*)&wb_s[c0 + lane * 4] = *(const float4*)&Wb[c0 + lane * 4];
    // no barrier needed: each wave touches only its own 256 cols until the end

    int g = blockIdx.x;
    int gs = goff[g], ge = goff[g + 1];

    for (int i0 = gs; i0 < ge; i0 += 32) {
        bf16x8 a00, a01, a10, a11;
        {
            const ushort* p0 = updbf + (size_t)(i0 + sl) * AF + G * 8;
            a00 = *(const bf16x8*)p0;
            a01 = *(const bf16x8*)(p0 + 32);
            const ushort* p1 = updbf + (size_t)(i0 + 16 + sl) * AF + G * 8;
            a10 = *(const bf16x8*)p1;
            a11 = *(const bf16x8*)(p1 + 32);
        }
        float sc0[4], sc1[4];
        #pragma unroll
        for (int r = 0; r < 4; ++r) {
            int n0 = i0 + G * 4 + r;
            sc0[r] = (n0 < ge) ? sden[n0] : 0.f;
            int n1 = n0 + 16;
            sc1[r] = (n1 < ge) ? sden[n1] : 0.f;
        }
        #pragma unroll 2
        for (int ct = 0; ct < 16; ++ct) {
            int col = c0 + ct * 16 + sl;
            const ushort* wp = Wbf + (size_t)col * AF + G * 8;
            bf16x8 b0 = *(const bf16x8*)wp;
            bf16x8 b1 = *(const bf16x8*)(wp + 32);
            float bias = wb_s[col];
            f32x4 d0 = {0.f, 0.f, 0.f, 0.f};
            d0 = __builtin_amdgcn_mfma_f32_16x16x32_bf16(a00, b0, d0, 0, 0, 0);
            d0 = __builtin_amdgcn_mfma_f32_16x16x32_bf16(a01, b1, d0, 0, 0, 0);
            f32x4 d1 = {0.f, 0.f, 0.f, 0.f};
            d1 = __builtin_amdgcn_mfma_f32_16x16x32_bf16(a10, b0, d1, 0, 0, 0);
            d1 = __builtin_amdgcn_mfma_f32_16x16x32_bf16(a11, b1, d1, 0, 0, 0);
            float c = 0.f;
            #pragma unroll
            for (int r = 0; r < 4; ++r) {
                c += __expf(d0[r] + bias) * sc0[r];
                c += __expf(d1[r] + bias) * sc1[r];
            }
            c += __shfl_xor(c, 16);
            c += __shfl_xor(c, 32);
            if (G == 0) facc[col] += c;   // exclusive (wave, ct, sl) -> col
        }
    }

    __syncthreads();
    float4 fa = *(float4*)&facc[t * 4];
    float* po = &out[(size_t)g * NFP];
    if (ACCUM) {
        float4 oa = *(const float4*)&po[t * 4];
        fa.x += oa.x; fa.y += oa.y; fa.z += oa.z; fa.w += oa.w;
    }
    *(float4*)&po[t * 4] = fa;
}

// ---------------------------------------------------------------------------
extern "C" void kernel_launch(void* const* d_in, const int* in_sizes, int n_in,
                              void* d_out, int out_size, void* d_ws, size_t ws_size,
                              hipStream_t stream)
{
    const float* x    = (const float*)d_in[0];
    const float* H1_w = (const float*)d_in[1];
    const float* H1_b = (const float*)d_in[2];
    const float* W1_w = (const float*)d_in[3];
    const float* W1_b = (const float*)d_in[4];
    const float* H2_w = (const float*)d_in[5];
    const float* H2_b = (const float*)d_in[6];
    const float* W2_w = (const float*)d_in[7];
    const float* W2_b = (const float*)d_in[8];
    const int*   ei   = (const int*)d_in[9];
    const int*   batch= (const int*)d_in[10];

    const int n_nodes  = in_sizes[0] / AF;   // 50000
    const int n_edges  = in_sizes[9] / 2;    // 1600000
    const int n_graphs = out_size / NFP;     // 2000
    const int npad     = ((n_nodes + 127) / 128) * 128;   // 50048
    const int* src = ei;
    const int* dst = ei + n_edges;
    float* out = (float*)d_out;

    // workspace layout
    float*  bufA    = (float*)d_ws;                          // n*64 f
    float*  bufB    = bufA + (size_t)n_nodes * AF;           // n*64 f
    float*  sden    = bufB + (size_t)n_nodes * AF;           // npad f
    ushort* updbf   = (ushort*)(sden + npad);                // npad*64 ush
    ushort* Wbf1    = updbf + (size_t)npad * AF;             // 131072 ush
    ushort* Wbf2    = Wbf1 + (size_t)NFP * AF;               // 131072 ush
    int*    offsets = (int*)(Wbf2 + (size_t)NFP * AF);       // n_nodes+1
    int*    cursor  = offsets + (n_nodes + 1);               // n_nodes+1
    int*    goff    = cursor + (n_nodes + 1);                // n_graphs+1
    int*    esrc    = goff + (n_graphs + 1);                 // n_edges

    const int eb = (n_edges + 255) / 256;
    const int nb = (n_nodes + 255) / 256;
    const int mlp_blocks = (n_nodes + 3) / 4;
    const int dn_blocks  = npad / 128;
    const int wn = NFP * AF;                 // 131072

    // --- one-time per launch: bf16 weights + CSR + graph offsets + pad ---
    f2bf_kernel<<<(wn + 255) / 256, 256, 0, stream>>>(W1_w, Wbf1, wn);
    f2bf_kernel<<<(wn + 255) / 256, 256, 0, stream>>>(W2_w, Wbf2, wn);
    hipMemsetAsync(updbf + (size_t)n_nodes * AF, 0,
                   (size_t)(npad - n_nodes) * AF * sizeof(ushort), stream);
    hipMemsetAsync(offsets, 0, (size_t)(n_nodes + 1) * sizeof(int), stream);
    hipMemsetAsync(goff, 0, (size_t)(n_graphs + 1) * sizeof(int), stream);
    hist_kernel<<<eb, 256, 0, stream>>>(dst, offsets, n_edges);
    hist_kernel<<<nb, 256, 0, stream>>>(batch, goff, n_nodes);
    scan_kernel<<<1, 1024, 0, stream>>>(offsets, n_nodes);
    scan_kernel<<<1, 1024, 0, stream>>>(goff, n_graphs);
    hipMemcpyAsync(cursor, offsets, (size_t)n_nodes * sizeof(int),
                   hipMemcpyDeviceToDevice, stream);
    scatter_ids_kernel<<<eb, 256, 0, stream>>>(src, dst, cursor, esrc, n_edges);

    // --- layer 1 ---
    agg_mlp_kernel<<<mlp_blocks, 256, 0, stream>>>(x, offsets, esrc, H1_w, H1_b,
                                                   bufB, updbf, n_nodes);
    denom_kernel<<<dn_blocks, 256, 0, stream>>>(updbf, Wbf1, W1_b, sden, n_nodes);
    fp_pool_graph_kernel<0><<<n_graphs, 512, 0, stream>>>(updbf, Wbf1, W1_b,
                                                          sden, goff, out);

    // --- layer 2 ---
    agg_mlp_kernel<<<mlp_blocks, 256, 0, stream>>>(bufB, offsets, esrc, H2_w, H2_b,
                                                   bufA, updbf, n_nodes);
    denom_kernel<<<dn_blocks, 256, 0, stream>>>(updbf, Wbf2, W2_b, sden, n_nodes);
    fp_pool_graph_kernel<1><<<n_graphs, 512, 0, stream>>>(updbf, Wbf2, W2_b,
                                                          sden, goff, out);
}

// Round 8
// 671.449 us; speedup vs baseline: 11.0315x; 1.1027x over previous
//
#include <hip/hip_runtime.h>
#include <hip/hip_bf16.h>

// N_NODES=50000, N_EDGES=1600000, ATOM_F=64, FP_SIZE=2048, N_GRAPHS=2000
#define AF 64
#define NFP 2048

typedef __attribute__((ext_vector_type(8))) short bf16x8;
typedef __attribute__((ext_vector_type(4))) float f32x4;

__device__ __forceinline__ ushort f2bf(float f) {
    unsigned u = __float_as_uint(f);
    return (ushort)((u + 0x7FFF + ((u >> 16) & 1)) >> 16);   // RNE
}
__device__ __forceinline__ float bf2f(ushort u) {
    return __uint_as_float((unsigned)u << 16);
}

// ---------------------------------------------------------------------------
// Generic histogram (int32 keys) — used for graph offsets (small)
// ---------------------------------------------------------------------------
__global__ __launch_bounds__(256) void hist_kernel(
    const int* __restrict__ keys, int* __restrict__ counts, int n)
{
    int e = blockIdx.x * 256 + threadIdx.x;
    if (e < n) atomicAdd(&counts[keys[e]], 1);
}

// XCD-partitioned histogram: block (chunk c, range r=blockIdx&7) touches only
// counters in its dst-range -> atomic/line traffic stays XCD-local.
__global__ __launch_bounds__(256) void hist_part_kernel(
    const int* __restrict__ dst, int* __restrict__ counts,
    int n_edges, int npr, int nchunks)
{
    int r = blockIdx.x & 7;
    int c = blockIdx.x >> 3;
    int lo = r * npr, hi = lo + npr;
    int per = (n_edges + nchunks - 1) / nchunks;
    int e0 = c * per;
    int e1 = e0 + per; if (e1 > n_edges) e1 = n_edges;
    for (int e = e0 + (int)threadIdx.x; e < e1; e += 256) {
        int d = dst[e];
        if (d >= lo && d < hi) atomicAdd(&counts[d], 1);
    }
}

// single-block exclusive scan, in place; data[n] = total
__global__ __launch_bounds__(1024) void scan_kernel(int* data, int n)
{
    __shared__ int wsum[16];
    __shared__ int chunk_total;
    int t = threadIdx.x, lane = t & 63, w = t >> 6;
    int running = 0;
    for (int base = 0; base < n; base += 1024) {
        int i = base + t;
        int v = (i < n) ? data[i] : 0;
        int x = v;
        #pragma unroll
        for (int off = 1; off < 64; off <<= 1) {
            int y = __shfl_up(x, off);
            if (lane >= off) x += y;
        }
        if (lane == 63) wsum[w] = x;
        __syncthreads();
        if (t == 0) {
            int s = 0;
            #pragma unroll
            for (int q = 0; q < 16; ++q) { int tmp = wsum[q]; wsum[q] = s; s += tmp; }
            chunk_total = s;
        }
        __syncthreads();
        if (i < n) data[i] = x - v + wsum[w] + running;
        running += chunk_total;
        __syncthreads();
    }
    if (t == 0) data[n] = running;
}

// XCD-partitioned id scatter: esrc region of range r written by r-blocks only.
__global__ __launch_bounds__(256) void scatter_part_kernel(
    const int* __restrict__ src, const int* __restrict__ dst,
    int* __restrict__ cursor, int* __restrict__ esrc,
    int n_edges, int npr, int nchunks)
{
    int r = blockIdx.x & 7;
    int c = blockIdx.x >> 3;
    int lo = r * npr, hi = lo + npr;
    int per = (n_edges + nchunks - 1) / nchunks;
    int e0 = c * per;
    int e1 = e0 + per; if (e1 > n_edges) e1 = n_edges;
    for (int e = e0 + (int)threadIdx.x; e < e1; e += 256) {
        int d = dst[e];
        if (d >= lo && d < hi) {
            int pos = atomicAdd(&cursor[d], 1);
            esrc[pos] = src[e];
        }
    }
}

// ---------------------------------------------------------------------------
// fp32 -> bf16 convert
// ---------------------------------------------------------------------------
__global__ __launch_bounds__(256) void f2bf_kernel(
    const float* __restrict__ W, ushort* __restrict__ Wbf, int n)
{
    int i = blockIdx.x * 256 + threadIdx.x;
    if (i < n) Wbf[i] = f2bf(W[i]);
}

// ---------------------------------------------------------------------------
// Fused gather-aggregate (CSR, bf16 rows = half the gather traffic) +
// self-loop + 64x64 sigmoid MLP (fp32 accum).  Output: bf16 node table only.
// 4 nodes per block (1/wave); 8 edges per wave-iteration (8 lanes x 16B).
// ---------------------------------------------------------------------------
__global__ __launch_bounds__(256) void agg_mlp_kernel(
    const ushort* __restrict__ hbf, const int* __restrict__ offsets,
    const int* __restrict__ esrc, const float* __restrict__ Hw,
    const float* __restrict__ Hb, ushort* __restrict__ outbf, int n_nodes)
{
    __shared__ float Hw_s[AF * 65];
    __shared__ __align__(16) float part[4][8][AF];   // 8 KB
    __shared__ float a_red[4][AF];
    __shared__ float hb_s[AF];

    int t = threadIdx.x;
    for (int idx = t; idx < AF * AF; idx += 256) {
        int j = idx >> 6, k = idx & 63;
        Hw_s[j * 65 + k] = Hw[idx];
    }
    if (t < AF) hb_s[t] = Hb[t];

    int w = t >> 6, lane = t & 63;
    int sub = lane >> 3, f8 = lane & 7;   // sub-edge slot, 8-ushort feature slot
    int i = blockIdx.x * 4 + w;

    float acc[8] = {0.f, 0.f, 0.f, 0.f, 0.f, 0.f, 0.f, 0.f};
    if (i < n_nodes) {
        int o0 = offsets[i], o1 = offsets[i + 1];
        const int* ep = esrc + o0;
        int deg = o1 - o0;
        for (int j = 0; j < deg; j += 8) {
            int jj = j + sub;
            if (jj < deg) {
                int s = ep[jj];
                bf16x8 v = *(const bf16x8*)(hbf + (size_t)s * AF + f8 * 8);
                #pragma unroll
                for (int q = 0; q < 8; ++q) acc[q] += bf2f((ushort)v[q]);
            }
        }
    }
    *(float4*)&part[w][sub][f8 * 8]     = make_float4(acc[0], acc[1], acc[2], acc[3]);
    *(float4*)&part[w][sub][f8 * 8 + 4] = make_float4(acc[4], acc[5], acc[6], acc[7]);
    __syncthreads();

    if (i < n_nodes) {
        float val = bf2f(hbf[(size_t)i * AF + lane]);   // self loop
        #pragma unroll
        for (int s8 = 0; s8 < 8; ++s8) val += part[w][s8][lane];
        a_red[w][lane] = val;
    }
    __syncthreads();

    if (i < n_nodes) {
        float z = hb_s[lane];
        #pragma unroll
        for (int k = 0; k < AF; ++k)
            z = fmaf(a_red[w][k], Hw_s[lane * 65 + k], z);
        float sg = 1.f / (1.f + __expf(-z));
        outbf[(size_t)i * AF + lane] = f2bf(sg);
    }
}

// ---------------------------------------------------------------------------
// Softmax denominators: sden[n] = 1 / sum_j exp(z_nj).  No max subtraction:
// upd in (0,1), ||W_row|| ~ 1  =>  |z| < ~10, exp safe in fp32.
// ---------------------------------------------------------------------------
__global__ __launch_bounds__(256) void denom_kernel(
    const ushort* __restrict__ updbf, const ushort* __restrict__ Wbf,
    const float* __restrict__ Wb, float* __restrict__ sden, int n_nodes)
{
    __shared__ float wb_s[NFP];
    int t = threadIdx.x, wave = t >> 6, lane = t & 63;
    int G = lane >> 4, sl = lane & 15;
    for (int i = t; i < NFP / 4; i += 256)
        *(float4*)&wb_s[i * 4] = *(const float4*)&Wb[i * 4];
    __syncthreads();

    int base = blockIdx.x * 128 + wave * 32;     // updbf padded past n_nodes
    bf16x8 a00, a01, a10, a11;
    {
        const ushort* p0 = updbf + (size_t)(base + sl) * AF + G * 8;
        a00 = *(const bf16x8*)p0;
        a01 = *(const bf16x8*)(p0 + 32);
        const ushort* p1 = updbf + (size_t)(base + 16 + sl) * AF + G * 8;
        a10 = *(const bf16x8*)p1;
        a11 = *(const bf16x8*)(p1 + 32);
    }
    float s0[4] = {0.f, 0.f, 0.f, 0.f};
    float s1[4] = {0.f, 0.f, 0.f, 0.f};

    #pragma unroll 2
    for (int ct = 0; ct < 128; ++ct) {
        int col = ct * 16 + sl;
        const ushort* wp = Wbf + (size_t)col * AF + G * 8;
        bf16x8 b0 = *(const bf16x8*)wp;
        bf16x8 b1 = *(const bf16x8*)(wp + 32);
        float bias = wb_s[col];
        f32x4 d0 = {0.f, 0.f, 0.f, 0.f};
        d0 = __builtin_amdgcn_mfma_f32_16x16x32_bf16(a00, b0, d0, 0, 0, 0);
        d0 = __builtin_amdgcn_mfma_f32_16x16x32_bf16(a01, b1, d0, 0, 0, 0);
        f32x4 d1 = {0.f, 0.f, 0.f, 0.f};
        d1 = __builtin_amdgcn_mfma_f32_16x16x32_bf16(a10, b0, d1, 0, 0, 0);
        d1 = __builtin_amdgcn_mfma_f32_16x16x32_bf16(a11, b1, d1, 0, 0, 0);
        #pragma unroll
        for (int r = 0; r < 4; ++r) {
            s0[r] += __expf(d0[r] + bias);
            s1[r] += __expf(d1[r] + bias);
        }
    }
    #pragma unroll
    for (int mask = 1; mask <= 8; mask <<= 1) {
        #pragma unroll
        for (int r = 0; r < 4; ++r) {
            s0[r] += __shfl_xor(s0[r], mask);
            s1[r] += __shfl_xor(s1[r], mask);
        }
    }
    if (sl == 0) {
        #pragma unroll
        for (int r = 0; r < 4; ++r) {
            int n0 = base + G * 4 + r;           // D row = G*4 + r
            if (n0 < n_nodes) sden[n0] = 1.f / s0[r];
            int n1 = n0 + 16;
            if (n1 < n_nodes) sden[n1] = 1.f / s1[r];
        }
    }
}

// ---------------------------------------------------------------------------
// Fingerprint pooling with precomputed denominators: one block per graph,
// out[g][j] = sum_{n in g} exp(z_nj) * sden[n].  No barriers in main loop,
// no z storage; wave owns its 256 cols of facc exclusively.
// ---------------------------------------------------------------------------
template <int ACCUM>
__global__ __launch_bounds__(512) void fp_pool_graph_kernel(
    const ushort* __restrict__ updbf, const ushort* __restrict__ Wbf,
    const float* __restrict__ Wb, const float* __restrict__ sden,
    const int* __restrict__ goff, float* __restrict__ out)
{
    __shared__ __align__(16) float facc[NFP];
    __shared__ __align__(16) float wb_s[NFP];

    int t = threadIdx.x, wave = t >> 6, lane = t & 63;
    int G = lane >> 4, sl = lane & 15;
    int c0 = wave * 256;

    *(float4*)&facc[c0 + lane * 4] = make_float4(0.f, 0.f, 0.f, 0.f);
    *(float4*)&wb_s[c0 + lane * 4] = *(const float4*)&Wb[c0 + lane * 4];

    int g = blockIdx.x;
    int gs = goff[g], ge = goff[g + 1];

    for (int i0 = gs; i0 < ge; i0 += 32) {
        bf16x8 a00, a01, a10, a11;
        {
            const ushort* p0 = updbf + (size_t)(i0 + sl) * AF + G * 8;
            a00 = *(const bf16x8*)p0;
            a01 = *(const bf16x8*)(p0 + 32);
            const ushort* p1 = updbf + (size_t)(i0 + 16 + sl) * AF + G * 8;
            a10 = *(const bf16x8*)p1;
            a11 = *(const bf16x8*)(p1 + 32);
        }
        float sc0[4], sc1[4];
        #pragma unroll
        for (int r = 0; r < 4; ++r) {
            int n0 = i0 + G * 4 + r;
            sc0[r] = (n0 < ge) ? sden[n0] : 0.f;
            int n1 = n0 + 16;
            sc1[r] = (n1 < ge) ? sden[n1] : 0.f;
        }
        #pragma unroll 2
        for (int ct = 0; ct < 16; ++ct) {
            int col = c0 + ct * 16 + sl;
            const ushort* wp = Wbf + (size_t)col * AF + G * 8;
            bf16x8 b0 = *(const bf16x8*)wp;
            bf16x8 b1 = *(const bf16x8*)(wp + 32);
            float bias = wb_s[col];
            f32x4 d0 = {0.f, 0.f, 0.f, 0.f};
            d0 = __builtin_amdgcn_mfma_f32_16x16x32_bf16(a00, b0, d0, 0, 0, 0);
            d0 = __builtin_amdgcn_mfma_f32_16x16x32_bf16(a01, b1, d0, 0, 0, 0);
            f32x4 d1 = {0.f, 0.f, 0.f, 0.f};
            d1 = __builtin_amdgcn_mfma_f32_16x16x32_bf16(a10, b0, d1, 0, 0, 0);
            d1 = __builtin_amdgcn_mfma_f32_16x16x32_bf16(a11, b1, d1, 0, 0, 0);
            float c = 0.f;
            #pragma unroll
            for (int r = 0; r < 4; ++r) {
                c += __expf(d0[r] + bias) * sc0[r];
                c += __expf(d1[r] + bias) * sc1[r];
            }
            c += __shfl_xor(c, 16);
            c += __shfl_xor(c, 32);
            if (G == 0) facc[col] += c;   // exclusive (wave, ct, sl) -> col
        }
    }

    __syncthreads();
    float4 fa = *(float4*)&facc[t * 4];
    float* po = &out[(size_t)g * NFP];
    if (ACCUM) {
        float4 oa = *(const float4*)&po[t * 4];
        fa.x += oa.x; fa.y += oa.y; fa.z += oa.z; fa.w += oa.w;
    }
    *(float4*)&po[t * 4] = fa;
}

// ---------------------------------------------------------------------------
extern "C" void kernel_launch(void* const* d_in, const int* in_sizes, int n_in,
                              void* d_out, int out_size, void* d_ws, size_t ws_size,
                              hipStream_t stream)
{
    const float* x    = (const float*)d_in[0];
    const float* H1_w = (const float*)d_in[1];
    const float* H1_b = (const float*)d_in[2];
    const float* W1_w = (const float*)d_in[3];
    const float* W1_b = (const float*)d_in[4];
    const float* H2_w = (const float*)d_in[5];
    const float* H2_b = (const float*)d_in[6];
    const float* W2_w = (const float*)d_in[7];
    const float* W2_b = (const float*)d_in[8];
    const int*   ei   = (const int*)d_in[9];
    const int*   batch= (const int*)d_in[10];

    const int n_nodes  = in_sizes[0] / AF;   // 50000
    const int n_edges  = in_sizes[9] / 2;    // 1600000
    const int n_graphs = out_size / NFP;     // 2000
    const int npad     = ((n_nodes + 127) / 128) * 128;   // 50048
    const int* src = ei;
    const int* dst = ei + n_edges;
    float* out = (float*)d_out;

    // workspace layout (all bf16 node tables; no fp32 node buffers)
    ushort* xbf     = (ushort*)d_ws;                     // npad*64
    ushort* ubf1    = xbf  + (size_t)npad * AF;          // npad*64
    ushort* ubf2    = ubf1 + (size_t)npad * AF;          // npad*64
    ushort* Wbf1    = ubf2 + (size_t)npad * AF;          // 131072
    ushort* Wbf2    = Wbf1 + (size_t)NFP * AF;           // 131072
    float*  sden    = (float*)(Wbf2 + (size_t)NFP * AF); // npad
    int*    offsets = (int*)(sden + npad);               // n_nodes+1
    int*    cursor  = offsets + (n_nodes + 1);           // n_nodes+1
    int*    goff    = cursor + (n_nodes + 1);            // n_graphs+1
    int*    esrc    = goff + (n_graphs + 1);             // n_edges

    const int nb = (n_nodes + 255) / 256;
    const int mlp_blocks = (n_nodes + 3) / 4;
    const int dn_blocks  = npad / 128;
    const int wn = NFP * AF;                 // 131072
    const int xn = n_nodes * AF;             // 3.2M
    const int npr = (n_nodes + 7) / 8;       // nodes per XCD-range
    const int nchunks = 256;                 // edge chunks per range sweep

    // --- one-time per launch: bf16 tables + CSR + graph offsets + pads ---
    f2bf_kernel<<<(xn + 255) / 256, 256, 0, stream>>>(x, xbf, xn);
    f2bf_kernel<<<(wn + 255) / 256, 256, 0, stream>>>(W1_w, Wbf1, wn);
    f2bf_kernel<<<(wn + 255) / 256, 256, 0, stream>>>(W2_w, Wbf2, wn);
    hipMemsetAsync(ubf1 + (size_t)n_nodes * AF, 0,
                   (size_t)(npad - n_nodes) * AF * sizeof(ushort), stream);
    hipMemsetAsync(ubf2 + (size_t)n_nodes * AF, 0,
                   (size_t)(npad - n_nodes) * AF * sizeof(ushort), stream);
    hipMemsetAsync(offsets, 0, (size_t)(n_nodes + 1) * sizeof(int), stream);
    hipMemsetAsync(goff, 0, (size_t)(n_graphs + 1) * sizeof(int), stream);
    hist_part_kernel<<<nchunks * 8, 256, 0, stream>>>(dst, offsets, n_edges, npr, nchunks);
    hist_kernel<<<nb, 256, 0, stream>>>(batch, goff, n_nodes);
    scan_kernel<<<1, 1024, 0, stream>>>(offsets, n_nodes);
    scan_kernel<<<1, 1024, 0, stream>>>(goff, n_graphs);
    hipMemcpyAsync(cursor, offsets, (size_t)n_nodes * sizeof(int),
                   hipMemcpyDeviceToDevice, stream);
    scatter_part_kernel<<<nchunks * 8, 256, 0, stream>>>(src, dst, cursor, esrc,
                                                         n_edges, npr, nchunks);

    // --- layer 1 ---
    agg_mlp_kernel<<<mlp_blocks, 256, 0, stream>>>(xbf, offsets, esrc,
                                                   H1_w, H1_b, ubf1, n_nodes);
    denom_kernel<<<dn_blocks, 256, 0, stream>>>(ubf1, Wbf1, W1_b, sden, n_nodes);
    fp_pool_graph_kernel<0><<<n_graphs, 512, 0, stream>>>(ubf1, Wbf1, W1_b,
                                                          sden, goff, out);

    // --- layer 2 ---
    agg_mlp_kernel<<<mlp_blocks, 256, 0, stream>>>(ubf1, offsets, esrc,
                                                   H2_w, H2_b, ubf2, n_nodes);
    denom_kernel<<<dn_blocks, 256, 0, stream>>>(ubf2, Wbf2, W2_b, sden, n_nodes);
    fp_pool_graph_kernel<1><<<n_graphs, 512, 0, stream>>>(ubf2, Wbf2, W2_b,
                                                          sden, goff, out);
}